// Round 2
// baseline (287.624 us; speedup 1.0000x reference)
//
#include <hip/hip_runtime.h>

// MeanPoolAggregator: out[n] = W @ mean_k(features[neigh_idx[n,k]])
// (mean-then-project — exact by linearity; 2x fewer FLOPs than project-first
//  since N_BATCH < N_UNIQUE, and needs NO workspace.)
//
// Fused single kernel:
//   - W [128][256] held in registers, distributed: thread owns 4 output rows
//     x 32-wide K-slice (128 VGPRs), loaded once per block.
//   - per node: coalesced gather-sum of 16 feature rows -> mf_lds[256],
//     register-W projection (128 FMA/thread, LDS broadcast reads),
//     cross-slice reduce via small LDS partial buffer, float4 store.

#define N_NODES  50000
#define N_UNIQUE 100000
#define KNEI     16
#define HID      256
#define POOL     128

#define NBLOCKS  512
#define NPB      ((N_NODES + NBLOCKS - 1) / NBLOCKS)   // 98 nodes per block

__global__ __launch_bounds__(256) void fused_meanpool_kernel(
    const int*   __restrict__ idx,    // [N_NODES][KNEI]  (int32 per harness contract)
    const float* __restrict__ feats,  // [N_UNIQUE][HID]
    const float* __restrict__ W,      // [POOL][HID]
    float* __restrict__ out)          // [N_NODES][POOL]
{
    __shared__ float  mf[HID];        // gathered sum for current node (1 KB)
    __shared__ float4 part[8][32];    // partials [ksl][og] (4 KB)

    const int tid = threadIdx.x;
    const int og  = tid & 31;         // output group: owns p = og*4 .. og*4+3
    const int ksl = tid >> 5;         // K-slice:     owns h = ksl*32 .. ksl*32+31

    // ---- load W slice into registers (one-time): w[e][j4] = W[og*4+e][ksl*32+j4*4 ..] ----
    float4 w[4][8];
#pragma unroll
    for (int e = 0; e < 4; ++e) {
        const float* wr = W + (size_t)(og * 4 + e) * HID + ksl * 32;
#pragma unroll
        for (int j4 = 0; j4 < 8; ++j4)
            w[e][j4] = *reinterpret_cast<const float4*>(wr + j4 * 4);
    }

    const int node0 = blockIdx.x * NPB;
    for (int i = 0; i < NPB; ++i) {
        const int node = node0 + i;          // block-uniform
        if (node >= N_NODES) break;          // uniform exit — barrier-safe

        // ---- phase 1: gather-sum 16 rows, thread t owns channel t (coalesced) ----
        const int* ip = idx + node * KNEI;   // uniform address -> scalar loads
        float v = 0.f;
#pragma unroll
        for (int k = 0; k < KNEI; ++k) {
            int r = ip[k];
            r = ((unsigned)r < (unsigned)N_UNIQUE) ? r : 0;   // crash-proof clamp
            v += feats[(size_t)r * HID + tid];
        }
        mf[tid] = v;
        __syncthreads();

        // ---- phase 2: projection against register-held W ----
        float4 acc = make_float4(0.f, 0.f, 0.f, 0.f);
        const float4* mfp = reinterpret_cast<const float4*>(&mf[ksl * 32]);
#pragma unroll
        for (int j4 = 0; j4 < 8; ++j4) {
            const float4 m4 = mfp[j4];       // 2 distinct addrs/wave -> ~free
            acc.x = fmaf(w[0][j4].x, m4.x, acc.x);
            acc.x = fmaf(w[0][j4].y, m4.y, acc.x);
            acc.x = fmaf(w[0][j4].z, m4.z, acc.x);
            acc.x = fmaf(w[0][j4].w, m4.w, acc.x);
            acc.y = fmaf(w[1][j4].x, m4.x, acc.y);
            acc.y = fmaf(w[1][j4].y, m4.y, acc.y);
            acc.y = fmaf(w[1][j4].z, m4.z, acc.y);
            acc.y = fmaf(w[1][j4].w, m4.w, acc.y);
            acc.z = fmaf(w[2][j4].x, m4.x, acc.z);
            acc.z = fmaf(w[2][j4].y, m4.y, acc.z);
            acc.z = fmaf(w[2][j4].z, m4.z, acc.z);
            acc.z = fmaf(w[2][j4].w, m4.w, acc.z);
            acc.w = fmaf(w[3][j4].x, m4.x, acc.w);
            acc.w = fmaf(w[3][j4].y, m4.y, acc.w);
            acc.w = fmaf(w[3][j4].z, m4.z, acc.w);
            acc.w = fmaf(w[3][j4].w, m4.w, acc.w);
        }
        part[ksl][og] = acc;
        __syncthreads();

        // ---- phase 3: reduce 8 K-slices, scale by 1/K, store ----
        if (tid < 32) {
            float4 s = part[0][tid];
#pragma unroll
            for (int k = 1; k < 8; ++k) {
                const float4 p4 = part[k][tid];
                s.x += p4.x; s.y += p4.y; s.z += p4.z; s.w += p4.w;
            }
            const float inv = 1.f / (float)KNEI;
            s.x *= inv; s.y *= inv; s.z *= inv; s.w *= inv;
            *reinterpret_cast<float4*>(out + (size_t)node * POOL + tid * 4) = s;
        }
        // no barrier needed here: next iter writes mf/part only after its own
        // __syncthreads(), and this thread's part-reads precede its next barrier.
    }
}

extern "C" void kernel_launch(void* const* d_in, const int* in_sizes, int n_in,
                              void* d_out, int out_size, void* d_ws, size_t ws_size,
                              hipStream_t stream) {
    const int*   idx   = (const int*)d_in[0];    // int32 (harness converts integer inputs)
    const float* feats = (const float*)d_in[1];  // fp32 [100000][256]
    const float* W     = (const float*)d_in[2];  // fp32 [128][256]
    float* out = (float*)d_out;                  // fp32 [50000][128]

    fused_meanpool_kernel<<<NBLOCKS, 256, 0, stream>>>(idx, feats, W, out);
}